// Round 7
// baseline (431.294 us; speedup 1.0000x reference)
//
#include <hip/hip_runtime.h>
#include <math.h>

#define CC 256   // columns
#define NN 512   // neurons per column
#define DD 256   // input dim (= D_CTX)
#define BB 64    // batch
#define KK 24    // top-k
#define WCAP 48  // winner-list capacity per row (>=24, slack for fp ties)

// ===========================================================================
// Kernel 0: xT[512][64]: d<256 -> x_in^T, d>=256 -> 0.3*x_ctx^T
// ===========================================================================
__global__ void transpose_x_kernel(const float* __restrict__ x_in,
                                   const float* __restrict__ x_ctx,
                                   float* __restrict__ xT) {
  int idx = blockIdx.x * blockDim.x + threadIdx.x;
  int d = idx >> 6;
  int b = idx & 63;
  float v = (d < DD) ? x_in[b * DD + d] : 0.3f * x_ctx[b * DD + (d - DD)];
  xT[idx] = v;
}

// ===========================================================================
// Kernel 1: boosted drive GEMM -> ws [C][B][N]
// grid = 2*CC (column x n-half), block = 512. Per-thread tile 4n x 8b:
//   per d-iter: 1 global dwordx4 (W) + 1 s_load_dwordx8 (x) + 32 FMA.
// Scalar bytes per FMA halved vs R6; wave d-stagger (start d = wave*32)
// de-phases the per-wave scalar-load streams (convoy breaker).
// ===========================================================================
__device__ __forceinline__ void gemm_pass(const float* __restrict__ wp,
                                          const float* __restrict__ xbase,
                                          int dlo, int dhi, float4 acc[8]) {
#pragma unroll 4
  for (int d = dlo; d < dhi; ++d) {
    const float4 w = *reinterpret_cast<const float4*>(wp + (size_t)d * NN);
    const float* __restrict__ xp = xbase + d * BB;  // wave-uniform -> s_load
#pragma unroll
    for (int i = 0; i < 8; ++i) {
      const float xv = xp[i];
      acc[i].x = fmaf(xv, w.x, acc[i].x);
      acc[i].y = fmaf(xv, w.y, acc[i].y);
      acc[i].z = fmaf(xv, w.z, acc[i].z);
      acc[i].w = fmaf(xv, w.w, acc[i].w);
    }
  }
}

__launch_bounds__(512)
__global__ void drive_gemm(const float* __restrict__ xT,      // [2D][B]
                           const float* __restrict__ W_ff,    // [C][D][N]
                           const float* __restrict__ W_ctx,   // [C][D][N]
                           const float* __restrict__ bias,    // [C][N]
                           const float* __restrict__ avg_act, // [C][N]
                           float* __restrict__ driveB) {      // [C][B][N]
  const int c = blockIdx.x >> 1;
  const int nh = blockIdx.x & 1;
  const int t = threadIdx.x;
  const int ng = t & 63;                        // 64 n-groups of 4
  const int n0 = nh * 256 + ng * 4;
  const int bg = t >> 6;                        // wave id 0..7
  const int b0 = __builtin_amdgcn_readfirstlane(bg * 8);   // 8 batches
  const int dstart = __builtin_amdgcn_readfirstlane(bg * 32);  // stagger

  float4 acc[8];
#pragma unroll
  for (int i = 0; i < 8; ++i) acc[i] = make_float4(0.f, 0.f, 0.f, 0.f);

  const float* __restrict__ wf = W_ff + (size_t)c * DD * NN + n0;
  const float* __restrict__ wc = W_ctx + (size_t)c * DD * NN + n0;
  const float* __restrict__ xf = xT + b0;
  const float* __restrict__ xc = xT + DD * BB + b0;

  gemm_pass(wf, xf, dstart, DD, acc);
  gemm_pass(wf, xf, 0, dstart, acc);
  gemm_pass(wc, xc, dstart, DD, acc);
  gemm_pass(wc, xc, 0, dstart, acc);

  const float4 bz = *reinterpret_cast<const float4*>(bias + (size_t)c * NN + n0);
  const float4 av = *reinterpret_cast<const float4*>(avg_act + (size_t)c * NN + n0);
  float4 bo;
  bo.x = log1pf(0.05f / (av.x + 1e-6f));
  bo.y = log1pf(0.05f / (av.y + 1e-6f));
  bo.z = log1pf(0.05f / (av.z + 1e-6f));
  bo.w = log1pf(0.05f / (av.w + 1e-6f));

#pragma unroll
  for (int i = 0; i < 8; ++i) {
    float4 m4;
    m4.x = (acc[i].x + bz.x) + bo.x;
    m4.y = (acc[i].y + bz.y) + bo.y;
    m4.z = (acc[i].z + bz.z) + bo.z;
    m4.w = (acc[i].w + bz.w) + bo.w;
    *reinterpret_cast<float4*>(driveB + ((size_t)c * BB + (b0 + i)) * NN + n0) = m4;
  }
}

// ===========================================================================
// Kernel 2: top-k + normalize + activations + sparse predictions + errors
// grid = 2*CC (column x batch-half), block = 512 (8 waves, 4 rows each)
// (unchanged — measured ~60 us)
// ===========================================================================
__launch_bounds__(512)
__global__ void sparse_pred(const float* __restrict__ x_in,    // [B][D]
                            const float* __restrict__ driveB,  // [C][B][N]
                            const float* __restrict__ W_pred,  // [C][N][D]
                            const float* __restrict__ avg_act, // [C][N]
                            float* __restrict__ out_act,       // [B][C][N]
                            float* __restrict__ out_pred,      // [B][C][D]
                            float* __restrict__ out_err) {     // [B][C][D]
  __shared__ int wcnt[32];
  __shared__ float wlist[32 * WCAP * 2];  // {val, idx-bits}

  const int c = blockIdx.x >> 1;
  const int bh = blockIdx.x & 1;  // batch half: rows bh*32 .. bh*32+31
  const int t = threadIdx.x;
  const int lane = t & 63;
  const int wv = t >> 6;  // 0..7

  float bo[8];
#pragma unroll
  for (int j = 0; j < 8; ++j)
    bo[j] = log1pf(0.05f / (avg_act[(size_t)c * NN + lane + 64 * j] + 1e-6f));

  for (int r = wv * 4; r < wv * 4 + 4; ++r) {  // local row 0..31
    const int b = bh * 32 + r;
    const float* __restrict__ row = driveB + ((size_t)c * BB + b) * NN;
    float o[8], v[8];
#pragma unroll
    for (int j = 0; j < 8; ++j) { o[j] = row[lane + 64 * j]; v[j] = o[j]; }

    float kth = 0.f;
    for (int it = 0; it < KK; ++it) {
      float m = v[0];
#pragma unroll
      for (int j = 1; j < 8; ++j) m = fmaxf(m, v[j]);
#pragma unroll
      for (int off = 1; off <= 32; off <<= 1) m = fmaxf(m, __shfl_xor(m, off));
      kth = m;
      bool mine = false;
#pragma unroll
      for (int j = 0; j < 8; ++j) mine = mine || (v[j] == m);
      unsigned long long msk = __ballot(mine);
      int first = __ffsll(msk) - 1;
      if (lane == first) {
        bool done = false;
#pragma unroll
        for (int j = 0; j < 8; ++j) {
          bool cnd = (!done) && (v[j] == m);
          if (cnd) v[j] = -INFINITY;
          done = done || cnd;
        }
      }
    }

    float raw[8];
    float s = 0.f;
#pragma unroll
    for (int j = 0; j < 8; ++j) {
      const float rw = (o[j] >= kth) ? fmaxf(o[j] - bo[j], 0.f) : 0.f;
      raw[j] = rw;
      s += rw;
    }
#pragma unroll
    for (int off = 1; off <= 32; off <<= 1) s += __shfl_xor(s, off);
    const float sc = (float)KK / (s + 1e-8f);

    int base = 0;
#pragma unroll
    for (int j = 0; j < 8; ++j) {
      const int n = lane + 64 * j;
      const float a = raw[j] * sc;
      out_act[(size_t)b * (CC * NN) + (size_t)c * NN + n] = a;
      const bool win = a > 0.f;
      unsigned long long m = __ballot(win);
      int pos = base + __popcll(m & ((1ull << lane) - 1ull));
      if (win && pos < WCAP) {
        const int slot = (r * WCAP + pos) * 2;
        wlist[slot] = a;
        reinterpret_cast<int*>(wlist)[slot + 1] = n;
      }
      base += (int)__popcll(m);
    }
    if (lane == 0) wcnt[r] = (base < WCAP) ? base : WCAP;
  }
  __syncthreads();

  {
    const int dq = t & 63;
    const int d0 = dq * 4;
    const int grp = t >> 6;  // 0..7 -> 4 local rows each
    const float* __restrict__ wp = W_pred + (size_t)c * NN * DD;
    for (int bi = 0; bi < 4; ++bi) {
      const int r = grp * 4 + bi;
      const int b = bh * 32 + r;
      const int cnt = wcnt[r];
      float4 p0 = make_float4(0.f, 0.f, 0.f, 0.f);
      float4 p1 = make_float4(0.f, 0.f, 0.f, 0.f);
      float4 p2 = make_float4(0.f, 0.f, 0.f, 0.f);
      float4 p3 = make_float4(0.f, 0.f, 0.f, 0.f);
      int i = 0;
      for (; i + 4 <= cnt; i += 4) {
        const int s0 = (r * WCAP + i) * 2;
        const float a0 = wlist[s0 + 0];
        const int n0 = reinterpret_cast<const int*>(wlist)[s0 + 1];
        const float a1 = wlist[s0 + 2];
        const int n1 = reinterpret_cast<const int*>(wlist)[s0 + 3];
        const float a2 = wlist[s0 + 4];
        const int n2 = reinterpret_cast<const int*>(wlist)[s0 + 5];
        const float a3 = wlist[s0 + 6];
        const int n3 = reinterpret_cast<const int*>(wlist)[s0 + 7];
        const float4 w0 = *reinterpret_cast<const float4*>(wp + (size_t)n0 * DD + d0);
        const float4 w1 = *reinterpret_cast<const float4*>(wp + (size_t)n1 * DD + d0);
        const float4 w2 = *reinterpret_cast<const float4*>(wp + (size_t)n2 * DD + d0);
        const float4 w3 = *reinterpret_cast<const float4*>(wp + (size_t)n3 * DD + d0);
        p0.x = fmaf(a0, w0.x, p0.x); p0.y = fmaf(a0, w0.y, p0.y);
        p0.z = fmaf(a0, w0.z, p0.z); p0.w = fmaf(a0, w0.w, p0.w);
        p1.x = fmaf(a1, w1.x, p1.x); p1.y = fmaf(a1, w1.y, p1.y);
        p1.z = fmaf(a1, w1.z, p1.z); p1.w = fmaf(a1, w1.w, p1.w);
        p2.x = fmaf(a2, w2.x, p2.x); p2.y = fmaf(a2, w2.y, p2.y);
        p2.z = fmaf(a2, w2.z, p2.z); p2.w = fmaf(a2, w2.w, p2.w);
        p3.x = fmaf(a3, w3.x, p3.x); p3.y = fmaf(a3, w3.y, p3.y);
        p3.z = fmaf(a3, w3.z, p3.z); p3.w = fmaf(a3, w3.w, p3.w);
      }
      for (; i < cnt; ++i) {
        const int s0 = (r * WCAP + i) * 2;
        const float a0 = wlist[s0];
        const int n0 = reinterpret_cast<const int*>(wlist)[s0 + 1];
        const float4 w0 = *reinterpret_cast<const float4*>(wp + (size_t)n0 * DD + d0);
        p0.x = fmaf(a0, w0.x, p0.x); p0.y = fmaf(a0, w0.y, p0.y);
        p0.z = fmaf(a0, w0.z, p0.z); p0.w = fmaf(a0, w0.w, p0.w);
      }
      float4 r4;
      r4.x = (p0.x + p1.x) + (p2.x + p3.x);
      r4.y = (p0.y + p1.y) + (p2.y + p3.y);
      r4.z = (p0.z + p1.z) + (p2.z + p3.z);
      r4.w = (p0.w + p1.w) + (p2.w + p3.w);
      const float4 xi = *reinterpret_cast<const float4*>(x_in + (size_t)b * DD + d0);
      float4 e4;
      e4.x = xi.x - r4.x; e4.y = xi.y - r4.y; e4.z = xi.z - r4.z; e4.w = xi.w - r4.w;
      *reinterpret_cast<float4*>(out_pred + (size_t)b * (CC * DD) + (size_t)c * DD + d0) = r4;
      *reinterpret_cast<float4*>(out_err + (size_t)b * (CC * DD) + (size_t)c * DD + d0) = e4;
    }
  }
}

// ===========================================================================
// Fallback fused kernel (R2, proven) for small ws_size
// ===========================================================================
#define MAT_F (BB * NN)
#define FSMEM_FLOATS (MAT_F + BB + BB + NN + BB + BB * WCAP * 2)
#define FSMEM_BYTES (FSMEM_FLOATS * 4)

__launch_bounds__(1024)
__global__ void cortical_fused(const float* __restrict__ x_in,
                               const float* __restrict__ xT,
                               const float* __restrict__ W_ff,
                               const float* __restrict__ W_ctx,
                               const float* __restrict__ W_pred,
                               const float* __restrict__ bias,
                               const float* __restrict__ avg_act,
                               float* __restrict__ out_act,
                               float* __restrict__ out_pred,
                               float* __restrict__ out_err) {
  extern __shared__ float smem[];
  float* mat = smem;
  float* thr = smem + MAT_F;
  float* scl = thr + BB;
  float* boostS = scl + BB;
  int* wcnt = (int*)(boostS + NN);
  float* wlist = (float*)(wcnt + BB);

  const int c = blockIdx.x;
  const int t = threadIdx.x;
  const int lane = t & 63;
  const int wv = t >> 6;

  if (t < NN) boostS[t] = log1pf(0.05f / (avg_act[c * NN + t] + 1e-6f));
  __syncthreads();

  const int ng = t & 255;
  const int n0 = ng * 2;
  const int b0 = __builtin_amdgcn_readfirstlane((t >> 8) * 16);

  float acc[16][2];
#pragma unroll
  for (int i = 0; i < 16; ++i) { acc[i][0] = 0.f; acc[i][1] = 0.f; }

  const float* __restrict__ wf = W_ff + (size_t)c * DD * NN + n0;
  const float* __restrict__ wc = W_ctx + (size_t)c * DD * NN + n0;

#pragma unroll 4
  for (int d = 0; d < DD; ++d) {
    const float2 w = *reinterpret_cast<const float2*>(wf + (size_t)d * NN);
    const float* __restrict__ xp = xT + d * BB + b0;
#pragma unroll
    for (int i = 0; i < 16; ++i) {
      const float xv = xp[i];
      acc[i][0] = fmaf(xv, w.x, acc[i][0]);
      acc[i][1] = fmaf(xv, w.y, acc[i][1]);
    }
  }
#pragma unroll 4
  for (int d = 0; d < DD; ++d) {
    const float2 w = *reinterpret_cast<const float2*>(wc + (size_t)d * NN);
    const float* __restrict__ xp = xT + (DD + d) * BB + b0;
#pragma unroll
    for (int i = 0; i < 16; ++i) {
      const float xv = xp[i];
      acc[i][0] = fmaf(xv, w.x, acc[i][0]);
      acc[i][1] = fmaf(xv, w.y, acc[i][1]);
    }
  }

  const float2 bz = *reinterpret_cast<const float2*>(bias + (size_t)c * NN + n0);
  const float2 bo = *reinterpret_cast<const float2*>(boostS + n0);
#pragma unroll
  for (int i = 0; i < 16; ++i) {
    float2 m2;
    m2.x = (acc[i][0] + bz.x) + bo.x;
    m2.y = (acc[i][1] + bz.y) + bo.y;
    *reinterpret_cast<float2*>(mat + (size_t)(b0 + i) * NN + n0) = m2;
  }
  __syncthreads();

  for (int r = wv * 4; r < wv * 4 + 4; ++r) {
    float v[8];
#pragma unroll
    for (int j = 0; j < 8; ++j) v[j] = mat[r * NN + lane + 64 * j];
    float kth = 0.f;
    for (int it = 0; it < KK; ++it) {
      float m = v[0];
#pragma unroll
      for (int j = 1; j < 8; ++j) m = fmaxf(m, v[j]);
#pragma unroll
      for (int off = 1; off <= 32; off <<= 1) m = fmaxf(m, __shfl_xor(m, off));
      kth = m;
      bool mine = false;
#pragma unroll
      for (int j = 0; j < 8; ++j) mine = mine || (v[j] == m);
      unsigned long long msk = __ballot(mine);
      int first = __ffsll(msk) - 1;
      if (lane == first) {
        bool done = false;
#pragma unroll
        for (int j = 0; j < 8; ++j) {
          bool cnd = (!done) && (v[j] == m);
          if (cnd) v[j] = -INFINITY;
          done = done || cnd;
        }
      }
    }
    if (lane == 0) thr[r] = kth;
  }
  __syncthreads();

  for (int r = wv * 4; r < wv * 4 + 4; ++r) {
    const float tb = thr[r];
    float raw[8];
    float s = 0.f;
#pragma unroll
    for (int j = 0; j < 8; ++j) {
      const int n = lane + 64 * j;
      const float bv = mat[r * NN + n];
      const float rw = (bv >= tb) ? fmaxf(bv - boostS[n], 0.f) : 0.f;
      raw[j] = rw;
      s += rw;
    }
#pragma unroll
    for (int off = 1; off <= 32; off <<= 1) s += __shfl_xor(s, off);
    const float sc = (float)KK / (s + 1e-8f);

    int base = 0;
#pragma unroll
    for (int j = 0; j < 8; ++j) {
      const int n = lane + 64 * j;
      const float a = raw[j] * sc;
      out_act[(size_t)r * (CC * NN) + (size_t)c * NN + n] = a;
      const bool win = a > 0.f;
      unsigned long long m = __ballot(win);
      int pos = base + __popcll(m & ((1ull << lane) - 1ull));
      if (win && pos < WCAP) {
        const int slot = (r * WCAP + pos) * 2;
        wlist[slot] = a;
        reinterpret_cast<int*>(wlist)[slot + 1] = n;
      }
      base += (int)__popcll(m);
    }
    if (lane == 0) wcnt[r] = (base < WCAP) ? base : WCAP;
  }
  __syncthreads();

  {
    const int dq = t & 63;
    const int d0 = dq * 4;
    const int grp = t >> 6;
    const float* __restrict__ wp = W_pred + (size_t)c * NN * DD;
    for (int bi = 0; bi < 4; ++bi) {
      const int b = grp * 4 + bi;
      const int cnt = wcnt[b];
      float4 p = make_float4(0.f, 0.f, 0.f, 0.f);
      float4 q = make_float4(0.f, 0.f, 0.f, 0.f);
      int i = 0;
      for (; i + 2 <= cnt; i += 2) {
        const int s0 = (b * WCAP + i) * 2;
        const int s1 = s0 + 2;
        const float a0 = wlist[s0];
        const int nn0 = reinterpret_cast<const int*>(wlist)[s0 + 1];
        const float a1 = wlist[s1];
        const int nn1 = reinterpret_cast<const int*>(wlist)[s1 + 1];
        const float4 w0 = *reinterpret_cast<const float4*>(wp + (size_t)nn0 * DD + d0);
        const float4 w1 = *reinterpret_cast<const float4*>(wp + (size_t)nn1 * DD + d0);
        p.x = fmaf(a0, w0.x, p.x); p.y = fmaf(a0, w0.y, p.y);
        p.z = fmaf(a0, w0.z, p.z); p.w = fmaf(a0, w0.w, p.w);
        q.x = fmaf(a1, w1.x, q.x); q.y = fmaf(a1, w1.y, q.y);
        q.z = fmaf(a1, w1.z, q.z); q.w = fmaf(a1, w1.w, q.w);
      }
      if (i < cnt) {
        const int s0 = (b * WCAP + i) * 2;
        const float a0 = wlist[s0];
        const int nn0 = reinterpret_cast<const int*>(wlist)[s0 + 1];
        const float4 w0 = *reinterpret_cast<const float4*>(wp + (size_t)nn0 * DD + d0);
        p.x = fmaf(a0, w0.x, p.x); p.y = fmaf(a0, w0.y, p.y);
        p.z = fmaf(a0, w0.z, p.z); p.w = fmaf(a0, w0.w, p.w);
      }
      float4 r4;
      r4.x = p.x + q.x; r4.y = p.y + q.y; r4.z = p.z + q.z; r4.w = p.w + q.w;
      const float4 xi = *reinterpret_cast<const float4*>(x_in + (size_t)b * DD + d0);
      float4 e4;
      e4.x = xi.x - r4.x; e4.y = xi.y - r4.y; e4.z = xi.z - r4.z; e4.w = xi.w - r4.w;
      *reinterpret_cast<float4*>(out_pred + (size_t)b * (CC * DD) + (size_t)c * DD + d0) = r4;
      *reinterpret_cast<float4*>(out_err + (size_t)b * (CC * DD) + (size_t)c * DD + d0) = e4;
    }
  }
}

extern "C" void kernel_launch(void* const* d_in, const int* in_sizes, int n_in,
                              void* d_out, int out_size, void* d_ws, size_t ws_size,
                              hipStream_t stream) {
  const float* x_in = (const float*)d_in[0];
  const float* x_ctx = (const float*)d_in[1];
  const float* W_ff = (const float*)d_in[2];
  const float* W_ctx = (const float*)d_in[3];
  const float* W_pred = (const float*)d_in[4];
  const float* bias = (const float*)d_in[5];
  const float* avg = (const float*)d_in[6];

  float* out = (float*)d_out;
  float* out_act = out;                              // [B][C][N]
  float* out_pred = out + (size_t)BB * CC * NN;      // [B][C][D]
  float* out_err = out_pred + (size_t)BB * CC * DD;  // [B][C][D]

  float* xT = (float*)d_ws;                          // [2*DD][BB]
  float* driveB = xT + 2 * BB * DD;                  // [C][B][N]

  const size_t need_bytes = (size_t)(2 * BB * DD + (size_t)CC * BB * NN) * 4;

  transpose_x_kernel<<<(2 * BB * DD) / 256, 256, 0, stream>>>(x_in, x_ctx, xT);

  if (ws_size >= need_bytes) {
    drive_gemm<<<2 * CC, 512, 0, stream>>>(xT, W_ff, W_ctx, bias, avg, driveB);
    sparse_pred<<<2 * CC, 512, 0, stream>>>(x_in, driveB, W_pred, avg, out_act,
                                            out_pred, out_err);
  } else {
    hipFuncSetAttribute((const void*)cortical_fused,
                        hipFuncAttributeMaxDynamicSharedMemorySize, FSMEM_BYTES);
    cortical_fused<<<CC, 1024, FSMEM_BYTES, stream>>>(x_in, xT, W_ff, W_ctx,
                                                      W_pred, bias, avg, out_act,
                                                      out_pred, out_err);
  }
}

// Round 8
// 253.359 us; speedup vs baseline: 1.7023x; 1.7023x over previous
//
#include <hip/hip_runtime.h>
#include <math.h>

#define CC 256   // columns
#define NN 512   // neurons per column
#define DD 256   // input dim (= D_CTX)
#define BB 64    // batch
#define KK 24    // top-k
#define WCAP 48  // winner-list capacity per row (>=24, slack for fp ties)

#define XSMEM_BYTES (2 * DD * BB * 4)  // 128 KiB x-tile in LDS

// ===========================================================================
// Kernel 0: xT[512][64]: d<256 -> x_in^T, d>=256 -> 0.3*x_ctx^T
// ===========================================================================
__global__ void transpose_x_kernel(const float* __restrict__ x_in,
                                   const float* __restrict__ x_ctx,
                                   float* __restrict__ xT) {
  int idx = blockIdx.x * blockDim.x + threadIdx.x;
  int d = idx >> 6;
  int b = idx & 63;
  float v = (d < DD) ? x_in[b * DD + d] : 0.3f * x_ctx[b * DD + (d - DD)];
  xT[idx] = v;
}

// ===========================================================================
// Kernel 1: boosted drive GEMM -> ws [C][B][N]
// grid = CC (one block per column), block = 1024, tile 2n x 16b (R3-proven).
// x is staged ONCE into 128 KB LDS; per-d x comes from 4 uniform-address
// ds_read_b128 (broadcast, conflict-free) instead of s_load — removes the
// SGPR-starved scalar-load serialization (the ~1600cyc/group stall in R3/R6).
// W-loads stay coalesced float2 per lane, same d-order as R3 (same numerics).
// ===========================================================================
__launch_bounds__(1024)
__global__ void drive_gemm(const float* __restrict__ xT,      // [2D][B]
                           const float* __restrict__ W_ff,    // [C][D][N]
                           const float* __restrict__ W_ctx,   // [C][D][N]
                           const float* __restrict__ bias,    // [C][N]
                           const float* __restrict__ avg_act, // [C][N]
                           float* __restrict__ driveB) {      // [C][B][N]
  extern __shared__ float xs[];  // [2*DD][BB]

  const int c = blockIdx.x;
  const int t = threadIdx.x;

  // ---- stage xT into LDS (32768 floats, 8 float4 per thread) --------------
  {
    const float4* __restrict__ src = reinterpret_cast<const float4*>(xT);
    float4* dst = reinterpret_cast<float4*>(xs);
#pragma unroll
    for (int i = 0; i < 8; ++i) dst[t + 1024 * i] = src[t + 1024 * i];
  }
  __syncthreads();

  const int ng = t & 255;   // 256 n-groups of 2
  const int n0 = ng * 2;
  const int bg = t >> 8;    // 0..3 (wave-uniform: 4 waves per bg)
  const int b0 = bg * 16;   // 16 batches

  float2 acc[16];
#pragma unroll
  for (int i = 0; i < 16; ++i) { acc[i].x = 0.f; acc[i].y = 0.f; }

  const float* __restrict__ wf = W_ff + (size_t)c * DD * NN + n0;
  const float* __restrict__ wc = W_ctx + (size_t)c * DD * NN + n0;

#pragma unroll 4
  for (int d = 0; d < DD; ++d) {
    const float2 w = *reinterpret_cast<const float2*>(wf + (size_t)d * NN);
    const float4* __restrict__ xp =
        reinterpret_cast<const float4*>(xs + d * BB + b0);  // uniform -> bcast
    const float4 x0 = xp[0], x1 = xp[1], x2 = xp[2], x3 = xp[3];
    acc[0].x = fmaf(x0.x, w.x, acc[0].x);  acc[0].y = fmaf(x0.x, w.y, acc[0].y);
    acc[1].x = fmaf(x0.y, w.x, acc[1].x);  acc[1].y = fmaf(x0.y, w.y, acc[1].y);
    acc[2].x = fmaf(x0.z, w.x, acc[2].x);  acc[2].y = fmaf(x0.z, w.y, acc[2].y);
    acc[3].x = fmaf(x0.w, w.x, acc[3].x);  acc[3].y = fmaf(x0.w, w.y, acc[3].y);
    acc[4].x = fmaf(x1.x, w.x, acc[4].x);  acc[4].y = fmaf(x1.x, w.y, acc[4].y);
    acc[5].x = fmaf(x1.y, w.x, acc[5].x);  acc[5].y = fmaf(x1.y, w.y, acc[5].y);
    acc[6].x = fmaf(x1.z, w.x, acc[6].x);  acc[6].y = fmaf(x1.z, w.y, acc[6].y);
    acc[7].x = fmaf(x1.w, w.x, acc[7].x);  acc[7].y = fmaf(x1.w, w.y, acc[7].y);
    acc[8].x = fmaf(x2.x, w.x, acc[8].x);  acc[8].y = fmaf(x2.x, w.y, acc[8].y);
    acc[9].x = fmaf(x2.y, w.x, acc[9].x);  acc[9].y = fmaf(x2.y, w.y, acc[9].y);
    acc[10].x = fmaf(x2.z, w.x, acc[10].x); acc[10].y = fmaf(x2.z, w.y, acc[10].y);
    acc[11].x = fmaf(x2.w, w.x, acc[11].x); acc[11].y = fmaf(x2.w, w.y, acc[11].y);
    acc[12].x = fmaf(x3.x, w.x, acc[12].x); acc[12].y = fmaf(x3.x, w.y, acc[12].y);
    acc[13].x = fmaf(x3.y, w.x, acc[13].x); acc[13].y = fmaf(x3.y, w.y, acc[13].y);
    acc[14].x = fmaf(x3.z, w.x, acc[14].x); acc[14].y = fmaf(x3.z, w.y, acc[14].y);
    acc[15].x = fmaf(x3.w, w.x, acc[15].x); acc[15].y = fmaf(x3.w, w.y, acc[15].y);
  }
#pragma unroll 4
  for (int d = 0; d < DD; ++d) {
    const float2 w = *reinterpret_cast<const float2*>(wc + (size_t)d * NN);
    const float4* __restrict__ xp =
        reinterpret_cast<const float4*>(xs + (DD + d) * BB + b0);
    const float4 x0 = xp[0], x1 = xp[1], x2 = xp[2], x3 = xp[3];
    acc[0].x = fmaf(x0.x, w.x, acc[0].x);  acc[0].y = fmaf(x0.x, w.y, acc[0].y);
    acc[1].x = fmaf(x0.y, w.x, acc[1].x);  acc[1].y = fmaf(x0.y, w.y, acc[1].y);
    acc[2].x = fmaf(x0.z, w.x, acc[2].x);  acc[2].y = fmaf(x0.z, w.y, acc[2].y);
    acc[3].x = fmaf(x0.w, w.x, acc[3].x);  acc[3].y = fmaf(x0.w, w.y, acc[3].y);
    acc[4].x = fmaf(x1.x, w.x, acc[4].x);  acc[4].y = fmaf(x1.x, w.y, acc[4].y);
    acc[5].x = fmaf(x1.y, w.x, acc[5].x);  acc[5].y = fmaf(x1.y, w.y, acc[5].y);
    acc[6].x = fmaf(x1.z, w.x, acc[6].x);  acc[6].y = fmaf(x1.z, w.y, acc[6].y);
    acc[7].x = fmaf(x1.w, w.x, acc[7].x);  acc[7].y = fmaf(x1.w, w.y, acc[7].y);
    acc[8].x = fmaf(x2.x, w.x, acc[8].x);  acc[8].y = fmaf(x2.x, w.y, acc[8].y);
    acc[9].x = fmaf(x2.y, w.x, acc[9].x);  acc[9].y = fmaf(x2.y, w.y, acc[9].y);
    acc[10].x = fmaf(x2.z, w.x, acc[10].x); acc[10].y = fmaf(x2.z, w.y, acc[10].y);
    acc[11].x = fmaf(x2.w, w.x, acc[11].x); acc[11].y = fmaf(x2.w, w.y, acc[11].y);
    acc[12].x = fmaf(x3.x, w.x, acc[12].x); acc[12].y = fmaf(x3.x, w.y, acc[12].y);
    acc[13].x = fmaf(x3.y, w.x, acc[13].x); acc[13].y = fmaf(x3.y, w.y, acc[13].y);
    acc[14].x = fmaf(x3.z, w.x, acc[14].x); acc[14].y = fmaf(x3.z, w.y, acc[14].y);
    acc[15].x = fmaf(x3.w, w.x, acc[15].x); acc[15].y = fmaf(x3.w, w.y, acc[15].y);
  }

  const float2 bz = *reinterpret_cast<const float2*>(bias + (size_t)c * NN + n0);
  const float2 av = *reinterpret_cast<const float2*>(avg_act + (size_t)c * NN + n0);
  float2 bo;
  bo.x = log1pf(0.05f / (av.x + 1e-6f));
  bo.y = log1pf(0.05f / (av.y + 1e-6f));

#pragma unroll
  for (int i = 0; i < 16; ++i) {
    float2 m2;
    m2.x = (acc[i].x + bz.x) + bo.x;
    m2.y = (acc[i].y + bz.y) + bo.y;
    *reinterpret_cast<float2*>(driveB + ((size_t)c * BB + (b0 + i)) * NN + n0) = m2;
  }
}

// ===========================================================================
// Kernel 2: top-k + normalize + activations + sparse predictions + errors
// grid = 2*CC (column x batch-half), block = 512 (8 waves, 4 rows each)
// (unchanged — proven)
// ===========================================================================
__launch_bounds__(512)
__global__ void sparse_pred(const float* __restrict__ x_in,    // [B][D]
                            const float* __restrict__ driveB,  // [C][B][N]
                            const float* __restrict__ W_pred,  // [C][N][D]
                            const float* __restrict__ avg_act, // [C][N]
                            float* __restrict__ out_act,       // [B][C][N]
                            float* __restrict__ out_pred,      // [B][C][D]
                            float* __restrict__ out_err) {     // [B][C][D]
  __shared__ int wcnt[32];
  __shared__ float wlist[32 * WCAP * 2];  // {val, idx-bits}

  const int c = blockIdx.x >> 1;
  const int bh = blockIdx.x & 1;  // batch half: rows bh*32 .. bh*32+31
  const int t = threadIdx.x;
  const int lane = t & 63;
  const int wv = t >> 6;  // 0..7

  float bo[8];
#pragma unroll
  for (int j = 0; j < 8; ++j)
    bo[j] = log1pf(0.05f / (avg_act[(size_t)c * NN + lane + 64 * j] + 1e-6f));

  for (int r = wv * 4; r < wv * 4 + 4; ++r) {  // local row 0..31
    const int b = bh * 32 + r;
    const float* __restrict__ row = driveB + ((size_t)c * BB + b) * NN;
    float o[8], v[8];
#pragma unroll
    for (int j = 0; j < 8; ++j) { o[j] = row[lane + 64 * j]; v[j] = o[j]; }

    float kth = 0.f;
    for (int it = 0; it < KK; ++it) {
      float m = v[0];
#pragma unroll
      for (int j = 1; j < 8; ++j) m = fmaxf(m, v[j]);
#pragma unroll
      for (int off = 1; off <= 32; off <<= 1) m = fmaxf(m, __shfl_xor(m, off));
      kth = m;
      bool mine = false;
#pragma unroll
      for (int j = 0; j < 8; ++j) mine = mine || (v[j] == m);
      unsigned long long msk = __ballot(mine);
      int first = __ffsll(msk) - 1;
      if (lane == first) {
        bool done = false;
#pragma unroll
        for (int j = 0; j < 8; ++j) {
          bool cnd = (!done) && (v[j] == m);
          if (cnd) v[j] = -INFINITY;
          done = done || cnd;
        }
      }
    }

    float raw[8];
    float s = 0.f;
#pragma unroll
    for (int j = 0; j < 8; ++j) {
      const float rw = (o[j] >= kth) ? fmaxf(o[j] - bo[j], 0.f) : 0.f;
      raw[j] = rw;
      s += rw;
    }
#pragma unroll
    for (int off = 1; off <= 32; off <<= 1) s += __shfl_xor(s, off);
    const float sc = (float)KK / (s + 1e-8f);

    int base = 0;
#pragma unroll
    for (int j = 0; j < 8; ++j) {
      const int n = lane + 64 * j;
      const float a = raw[j] * sc;
      out_act[(size_t)b * (CC * NN) + (size_t)c * NN + n] = a;
      const bool win = a > 0.f;
      unsigned long long m = __ballot(win);
      int pos = base + __popcll(m & ((1ull << lane) - 1ull));
      if (win && pos < WCAP) {
        const int slot = (r * WCAP + pos) * 2;
        wlist[slot] = a;
        reinterpret_cast<int*>(wlist)[slot + 1] = n;
      }
      base += (int)__popcll(m);
    }
    if (lane == 0) wcnt[r] = (base < WCAP) ? base : WCAP;
  }
  __syncthreads();

  {
    const int dq = t & 63;
    const int d0 = dq * 4;
    const int grp = t >> 6;  // 0..7 -> 4 local rows each
    const float* __restrict__ wp = W_pred + (size_t)c * NN * DD;
    for (int bi = 0; bi < 4; ++bi) {
      const int r = grp * 4 + bi;
      const int b = bh * 32 + r;
      const int cnt = wcnt[r];
      float4 p0 = make_float4(0.f, 0.f, 0.f, 0.f);
      float4 p1 = make_float4(0.f, 0.f, 0.f, 0.f);
      float4 p2 = make_float4(0.f, 0.f, 0.f, 0.f);
      float4 p3 = make_float4(0.f, 0.f, 0.f, 0.f);
      int i = 0;
      for (; i + 4 <= cnt; i += 4) {
        const int s0 = (r * WCAP + i) * 2;
        const float a0 = wlist[s0 + 0];
        const int n0 = reinterpret_cast<const int*>(wlist)[s0 + 1];
        const float a1 = wlist[s0 + 2];
        const int n1 = reinterpret_cast<const int*>(wlist)[s0 + 3];
        const float a2 = wlist[s0 + 4];
        const int n2 = reinterpret_cast<const int*>(wlist)[s0 + 5];
        const float a3 = wlist[s0 + 6];
        const int n3 = reinterpret_cast<const int*>(wlist)[s0 + 7];
        const float4 w0 = *reinterpret_cast<const float4*>(wp + (size_t)n0 * DD + d0);
        const float4 w1 = *reinterpret_cast<const float4*>(wp + (size_t)n1 * DD + d0);
        const float4 w2 = *reinterpret_cast<const float4*>(wp + (size_t)n2 * DD + d0);
        const float4 w3 = *reinterpret_cast<const float4*>(wp + (size_t)n3 * DD + d0);
        p0.x = fmaf(a0, w0.x, p0.x); p0.y = fmaf(a0, w0.y, p0.y);
        p0.z = fmaf(a0, w0.z, p0.z); p0.w = fmaf(a0, w0.w, p0.w);
        p1.x = fmaf(a1, w1.x, p1.x); p1.y = fmaf(a1, w1.y, p1.y);
        p1.z = fmaf(a1, w1.z, p1.z); p1.w = fmaf(a1, w1.w, p1.w);
        p2.x = fmaf(a2, w2.x, p2.x); p2.y = fmaf(a2, w2.y, p2.y);
        p2.z = fmaf(a2, w2.z, p2.z); p2.w = fmaf(a2, w2.w, p2.w);
        p3.x = fmaf(a3, w3.x, p3.x); p3.y = fmaf(a3, w3.y, p3.y);
        p3.z = fmaf(a3, w3.z, p3.z); p3.w = fmaf(a3, w3.w, p3.w);
      }
      for (; i < cnt; ++i) {
        const int s0 = (r * WCAP + i) * 2;
        const float a0 = wlist[s0];
        const int n0 = reinterpret_cast<const int*>(wlist)[s0 + 1];
        const float4 w0 = *reinterpret_cast<const float4*>(wp + (size_t)n0 * DD + d0);
        p0.x = fmaf(a0, w0.x, p0.x); p0.y = fmaf(a0, w0.y, p0.y);
        p0.z = fmaf(a0, w0.z, p0.z); p0.w = fmaf(a0, w0.w, p0.w);
      }
      float4 r4;
      r4.x = (p0.x + p1.x) + (p2.x + p3.x);
      r4.y = (p0.y + p1.y) + (p2.y + p3.y);
      r4.z = (p0.z + p1.z) + (p2.z + p3.z);
      r4.w = (p0.w + p1.w) + (p2.w + p3.w);
      const float4 xi = *reinterpret_cast<const float4*>(x_in + (size_t)b * DD + d0);
      float4 e4;
      e4.x = xi.x - r4.x; e4.y = xi.y - r4.y; e4.z = xi.z - r4.z; e4.w = xi.w - r4.w;
      *reinterpret_cast<float4*>(out_pred + (size_t)b * (CC * DD) + (size_t)c * DD + d0) = r4;
      *reinterpret_cast<float4*>(out_err + (size_t)b * (CC * DD) + (size_t)c * DD + d0) = e4;
    }
  }
}

// ===========================================================================
// Fallback fused kernel (R2, proven) for small ws_size
// ===========================================================================
#define MAT_F (BB * NN)
#define FSMEM_FLOATS (MAT_F + BB + BB + NN + BB + BB * WCAP * 2)
#define FSMEM_BYTES (FSMEM_FLOATS * 4)

__launch_bounds__(1024)
__global__ void cortical_fused(const float* __restrict__ x_in,
                               const float* __restrict__ xT,
                               const float* __restrict__ W_ff,
                               const float* __restrict__ W_ctx,
                               const float* __restrict__ W_pred,
                               const float* __restrict__ bias,
                               const float* __restrict__ avg_act,
                               float* __restrict__ out_act,
                               float* __restrict__ out_pred,
                               float* __restrict__ out_err) {
  extern __shared__ float smem[];
  float* mat = smem;
  float* thr = smem + MAT_F;
  float* scl = thr + BB;
  float* boostS = scl + BB;
  int* wcnt = (int*)(boostS + NN);
  float* wlist = (float*)(wcnt + BB);

  const int c = blockIdx.x;
  const int t = threadIdx.x;
  const int lane = t & 63;
  const int wv = t >> 6;

  if (t < NN) boostS[t] = log1pf(0.05f / (avg_act[c * NN + t] + 1e-6f));
  __syncthreads();

  const int ng = t & 255;
  const int n0 = ng * 2;
  const int b0 = __builtin_amdgcn_readfirstlane((t >> 8) * 16);

  float acc[16][2];
#pragma unroll
  for (int i = 0; i < 16; ++i) { acc[i][0] = 0.f; acc[i][1] = 0.f; }

  const float* __restrict__ wf = W_ff + (size_t)c * DD * NN + n0;
  const float* __restrict__ wc = W_ctx + (size_t)c * DD * NN + n0;

#pragma unroll 4
  for (int d = 0; d < DD; ++d) {
    const float2 w = *reinterpret_cast<const float2*>(wf + (size_t)d * NN);
    const float* __restrict__ xp = xT + d * BB + b0;
#pragma unroll
    for (int i = 0; i < 16; ++i) {
      const float xv = xp[i];
      acc[i][0] = fmaf(xv, w.x, acc[i][0]);
      acc[i][1] = fmaf(xv, w.y, acc[i][1]);
    }
  }
#pragma unroll 4
  for (int d = 0; d < DD; ++d) {
    const float2 w = *reinterpret_cast<const float2*>(wc + (size_t)d * NN);
    const float* __restrict__ xp = xT + (DD + d) * BB + b0;
#pragma unroll
    for (int i = 0; i < 16; ++i) {
      const float xv = xp[i];
      acc[i][0] = fmaf(xv, w.x, acc[i][0]);
      acc[i][1] = fmaf(xv, w.y, acc[i][1]);
    }
  }

  const float2 bz = *reinterpret_cast<const float2*>(bias + (size_t)c * NN + n0);
  const float2 bo = *reinterpret_cast<const float2*>(boostS + n0);
#pragma unroll
  for (int i = 0; i < 16; ++i) {
    float2 m2;
    m2.x = (acc[i][0] + bz.x) + bo.x;
    m2.y = (acc[i][1] + bz.y) + bo.y;
    *reinterpret_cast<float2*>(mat + (size_t)(b0 + i) * NN + n0) = m2;
  }
  __syncthreads();

  for (int r = wv * 4; r < wv * 4 + 4; ++r) {
    float v[8];
#pragma unroll
    for (int j = 0; j < 8; ++j) v[j] = mat[r * NN + lane + 64 * j];
    float kth = 0.f;
    for (int it = 0; it < KK; ++it) {
      float m = v[0];
#pragma unroll
      for (int j = 1; j < 8; ++j) m = fmaxf(m, v[j]);
#pragma unroll
      for (int off = 1; off <= 32; off <<= 1) m = fmaxf(m, __shfl_xor(m, off));
      kth = m;
      bool mine = false;
#pragma unroll
      for (int j = 0; j < 8; ++j) mine = mine || (v[j] == m);
      unsigned long long msk = __ballot(mine);
      int first = __ffsll(msk) - 1;
      if (lane == first) {
        bool done = false;
#pragma unroll
        for (int j = 0; j < 8; ++j) {
          bool cnd = (!done) && (v[j] == m);
          if (cnd) v[j] = -INFINITY;
          done = done || cnd;
        }
      }
    }
    if (lane == 0) thr[r] = kth;
  }
  __syncthreads();

  for (int r = wv * 4; r < wv * 4 + 4; ++r) {
    const float tb = thr[r];
    float raw[8];
    float s = 0.f;
#pragma unroll
    for (int j = 0; j < 8; ++j) {
      const int n = lane + 64 * j;
      const float bv = mat[r * NN + n];
      const float rw = (bv >= tb) ? fmaxf(bv - boostS[n], 0.f) : 0.f;
      raw[j] = rw;
      s += rw;
    }
#pragma unroll
    for (int off = 1; off <= 32; off <<= 1) s += __shfl_xor(s, off);
    const float sc = (float)KK / (s + 1e-8f);

    int base = 0;
#pragma unroll
    for (int j = 0; j < 8; ++j) {
      const int n = lane + 64 * j;
      const float a = raw[j] * sc;
      out_act[(size_t)r * (CC * NN) + (size_t)c * NN + n] = a;
      const bool win = a > 0.f;
      unsigned long long m = __ballot(win);
      int pos = base + __popcll(m & ((1ull << lane) - 1ull));
      if (win && pos < WCAP) {
        const int slot = (r * WCAP + pos) * 2;
        wlist[slot] = a;
        reinterpret_cast<int*>(wlist)[slot + 1] = n;
      }
      base += (int)__popcll(m);
    }
    if (lane == 0) wcnt[r] = (base < WCAP) ? base : WCAP;
  }
  __syncthreads();

  {
    const int dq = t & 63;
    const int d0 = dq * 4;
    const int grp = t >> 6;
    const float* __restrict__ wp = W_pred + (size_t)c * NN * DD;
    for (int bi = 0; bi < 4; ++bi) {
      const int b = grp * 4 + bi;
      const int cnt = wcnt[b];
      float4 p = make_float4(0.f, 0.f, 0.f, 0.f);
      float4 q = make_float4(0.f, 0.f, 0.f, 0.f);
      int i = 0;
      for (; i + 2 <= cnt; i += 2) {
        const int s0 = (b * WCAP + i) * 2;
        const int s1 = s0 + 2;
        const float a0 = wlist[s0];
        const int nn0 = reinterpret_cast<const int*>(wlist)[s0 + 1];
        const float a1 = wlist[s1];
        const int nn1 = reinterpret_cast<const int*>(wlist)[s1 + 1];
        const float4 w0 = *reinterpret_cast<const float4*>(wp + (size_t)nn0 * DD + d0);
        const float4 w1 = *reinterpret_cast<const float4*>(wp + (size_t)nn1 * DD + d0);
        p.x = fmaf(a0, w0.x, p.x); p.y = fmaf(a0, w0.y, p.y);
        p.z = fmaf(a0, w0.z, p.z); p.w = fmaf(a0, w0.w, p.w);
        q.x = fmaf(a1, w1.x, q.x); q.y = fmaf(a1, w1.y, q.y);
        q.z = fmaf(a1, w1.z, q.z); q.w = fmaf(a1, w1.w, q.w);
      }
      if (i < cnt) {
        const int s0 = (b * WCAP + i) * 2;
        const float a0 = wlist[s0];
        const int nn0 = reinterpret_cast<const int*>(wlist)[s0 + 1];
        const float4 w0 = *reinterpret_cast<const float4*>(wp + (size_t)nn0 * DD + d0);
        p.x = fmaf(a0, w0.x, p.x); p.y = fmaf(a0, w0.y, p.y);
        p.z = fmaf(a0, w0.z, p.z); p.w = fmaf(a0, w0.w, p.w);
      }
      float4 r4;
      r4.x = p.x + q.x; r4.y = p.y + q.y; r4.z = p.z + q.z; r4.w = p.w + q.w;
      const float4 xi = *reinterpret_cast<const float4*>(x_in + (size_t)b * DD + d0);
      float4 e4;
      e4.x = xi.x - r4.x; e4.y = xi.y - r4.y; e4.z = xi.z - r4.z; e4.w = xi.w - r4.w;
      *reinterpret_cast<float4*>(out_pred + (size_t)b * (CC * DD) + (size_t)c * DD + d0) = r4;
      *reinterpret_cast<float4*>(out_err + (size_t)b * (CC * DD) + (size_t)c * DD + d0) = e4;
    }
  }
}

extern "C" void kernel_launch(void* const* d_in, const int* in_sizes, int n_in,
                              void* d_out, int out_size, void* d_ws, size_t ws_size,
                              hipStream_t stream) {
  const float* x_in = (const float*)d_in[0];
  const float* x_ctx = (const float*)d_in[1];
  const float* W_ff = (const float*)d_in[2];
  const float* W_ctx = (const float*)d_in[3];
  const float* W_pred = (const float*)d_in[4];
  const float* bias = (const float*)d_in[5];
  const float* avg = (const float*)d_in[6];

  float* out = (float*)d_out;
  float* out_act = out;                              // [B][C][N]
  float* out_pred = out + (size_t)BB * CC * NN;      // [B][C][D]
  float* out_err = out_pred + (size_t)BB * CC * DD;  // [B][C][D]

  float* xT = (float*)d_ws;                          // [2*DD][BB]
  float* driveB = xT + 2 * BB * DD;                  // [C][B][N]

  const size_t need_bytes = (size_t)(2 * BB * DD + (size_t)CC * BB * NN) * 4;

  transpose_x_kernel<<<(2 * BB * DD) / 256, 256, 0, stream>>>(x_in, x_ctx, xT);

  if (ws_size >= need_bytes) {
    hipFuncSetAttribute((const void*)drive_gemm,
                        hipFuncAttributeMaxDynamicSharedMemorySize, XSMEM_BYTES);
    drive_gemm<<<CC, 1024, XSMEM_BYTES, stream>>>(xT, W_ff, W_ctx, bias, avg,
                                                  driveB);
    sparse_pred<<<2 * CC, 512, 0, stream>>>(x_in, driveB, W_pred, avg, out_act,
                                            out_pred, out_err);
  } else {
    hipFuncSetAttribute((const void*)cortical_fused,
                        hipFuncAttributeMaxDynamicSharedMemorySize, FSMEM_BYTES);
    cortical_fused<<<CC, 1024, FSMEM_BYTES, stream>>>(x_in, xT, W_ff, W_ctx,
                                                      W_pred, bias, avg, out_act,
                                                      out_pred, out_err);
  }
}